// Round 1
// baseline (166.422 us; speedup 1.0000x reference)
//
#include <hip/hip_runtime.h>

typedef __attribute__((ext_vector_type(8))) short short8;
typedef __attribute__((ext_vector_type(4))) float float4v;

__device__ __forceinline__ unsigned short f2bf(float f) {
    unsigned int x = __builtin_bit_cast(unsigned int, f);
    x += 0x7FFF + ((x >> 16) & 1);   // round-to-nearest-even
    return (unsigned short)(x >> 16);
}

struct __align__(16) U16x8 { unsigned short u[8]; };

// DPP cross-lane ops within 16-lane rows — pure VALU.
template <int CTRL>
__device__ __forceinline__ float dppmaxf(float x) {
    int y = __builtin_amdgcn_update_dpp(0, __builtin_bit_cast(int, x),
                                        CTRL, 0xF, 0xF, true);
    return fmaxf(x, __builtin_bit_cast(float, y));
}
template <int CTRL>
__device__ __forceinline__ float dppaddf(float x) {
    int y = __builtin_amdgcn_update_dpp(0, __builtin_bit_cast(int, x),
                                        CTRL, 0xF, 0xF, true);
    return x + __builtin_bit_cast(float, y);
}
__device__ __forceinline__ float rowmax16(float x) {
    x = dppmaxf<0xB1>(x);    // quad_perm [1,0,3,2]
    x = dppmaxf<0x4E>(x);    // quad_perm [2,3,0,1]
    x = dppmaxf<0x141>(x);   // row_half_mirror
    x = dppmaxf<0x140>(x);   // row_mirror
    return x;
}
__device__ __forceinline__ float rowsum16(float x) {
    x = dppaddf<0xB1>(x);
    x = dppaddf<0x4E>(x);
    x = dppaddf<0x141>(x);
    x = dppaddf<0x140>(x);
    return x;
}
__device__ __forceinline__ float wavesum64(float x) {
    x = rowsum16(x);
    x += __shfl_xor(x, 16, 64);
    x += __shfl_xor(x, 32, 64);
    return x;
}

// Kernel 0: f32 [img][64c][256s] -> bf16 [img][s][c] with chunk XOR swizzle
// (chunk' = (c/8) ^ (s%8)). imgs 0..47 = probe, 48..95 = gallery.
// 384 single-wave blocks: img = bid>>2, s-quarter = bid&3.
// Also zeroes the last-block ticket counter (workspace is re-poisoned
// between graph replays, so this must happen every iteration; stream
// order makes it visible to score_pam's device-scope atomics).
__global__ __launch_bounds__(64) void pretranspose_kernel(
    const float* __restrict__ prob,
    const float* __restrict__ gal,
    unsigned short* __restrict__ outT,   // [96][16384] bf16
    unsigned int* __restrict__ cnt)
{
    if (blockIdx.x == 0 && threadIdx.x == 0) *cnt = 0u;
    const int img = blockIdx.x >> 2;
    const int quarter = blockIdx.x & 3;
    const float* src = (img < 48) ? (prob + img * 16384)
                                  : (gal + (img - 48) * 16384);
    unsigned short* dst = outT + img * 16384;
    const int tid = threadIdx.x;          // 0..63
    const int c0 = (tid & 7) * 8;
    const int s0 = quarter * 64 + (tid >> 3) * 8;
    unsigned short v[8][8];
#pragma unroll
    for (int i = 0; i < 8; ++i) {
        const float* p = src + (c0 + i) * 256 + s0;
        const float4v f0 = *(const float4v*)(p);
        const float4v f1 = *(const float4v*)(p + 4);
        v[i][0] = f2bf(f0.x); v[i][1] = f2bf(f0.y);
        v[i][2] = f2bf(f0.z); v[i][3] = f2bf(f0.w);
        v[i][4] = f2bf(f1.x); v[i][5] = f2bf(f1.y);
        v[i][6] = f2bf(f1.z); v[i][7] = f2bf(f1.w);
    }
#pragma unroll
    for (int j = 0; j < 8; ++j) {
        U16x8 o;
#pragma unroll
        for (int i = 0; i < 8; ++i) o.u[i] = v[i][j];
        const int srow = s0 + j;
        const int off = srow * 64 + (((c0 >> 3) ^ (srow & 7)) << 3);
        *(U16x8*)(dst + off) = o;
    }
}

// Kernel A: ONE WAVE = ONE PAIR, entire probe image register-resident
// (32 KB = 128 VGPRs: B0[16]+B1[16] short8). Branch-free full unroll,
// zero LDS, zero barriers. acc.i = score(r = rt*16+q*4+i, s = ct*16+laneM).
//
// NEW (this round): the finalize kernel is FUSED via the last-block
// pattern. After each wave stores its (dot,sum,sq), lane 0 takes a
// device-scope ticket; the wave drawing ticket 2303 acquires (second
// __threadfence crosses the non-coherent per-XCD L2s) and runs the
// whole BN1+fc+pairsum+BN2+sigmoid epilogue in 64 lanes (36 pairs/lane).
// This removes one dispatch + its graph dependency gap and overlaps the
// finalize latency with the score kernel's own drain.
__global__ __launch_bounds__(64, 2) void score_pam_kernel(
    const unsigned short* __restrict__ preT,  // [96][16384] bf16 pre-transposed
    const float* __restrict__ fcw,            // [256] f32
    float* __restrict__ outDot,               // [2304]
    float* __restrict__ outSum,               // [2304]
    float* __restrict__ outSq,                // [2304]
    unsigned int* __restrict__ cnt,           // ticket counter (zeroed by k0)
    const float* __restrict__ bng,
    const float* __restrict__ bnb,
    const float* __restrict__ fcb,
    const float* __restrict__ lg,
    const float* __restrict__ lb,
    float* __restrict__ outp)                 // [2304] f32 final output
{
    constexpr int cLOW[16] = {0,0,0,1,2,3,4,5,6,7,8,9,10,11,12,12};
    constexpr int cHIW[16] = {3,3,3,4,5,6,7,8,9,10,11,12,13,14,15,15};

    const int lane = threadIdx.x;              // 0..63 (one wave)
    const int bid = blockIdx.x;                // 0..2303
    const int pair = (bid & 255) * 9 + (bid >> 8);   // CU-affine bijection
    const int ip = pair / 48;
    const int ig = pair % 48;
    const unsigned short* pimg = preT + ip * 16384;         // B: probe (cols)
    const unsigned short* gimg = preT + (48 + ig) * 16384;  // A: gallery (rows)

    const int laneM = lane & 15;
    const int q = lane >> 4;
    const int z = laneM & 7;
    const int ch0 = (q ^ z) << 3;
    const int ch1 = ((q + 4) ^ z) << 3;

    // ---- register-resident probe: 32 independent loads, 128 VGPRs
    short8 B0[16], B1[16];
#pragma unroll
    for (int ct = 0; ct < 16; ++ct) {
        const int sl = ct * 16 + laneM;
        B0[ct] = *(const short8*)(pimg + sl * 64 + ch0);
        B1[ct] = *(const short8*)(pimg + sl * 64 + ch1);
    }

    float dot = 0.f, sum = 0.f, sq = 0.f;
    const float msk = (laneM == 0) ? 1.0f : 0.0f;   // one lane per s2 row copy
    const float msk1 = (q == 0) ? 1.0f : 0.0f;      // one quad per s1 col copy

    float s1p[16];
#pragma unroll
    for (int i = 0; i < 16; ++i) s1p[i] = -3.0e38f;

#pragma unroll
    for (int rt = 0; rt < 16; ++rt) {
        const int srow = rt * 16 + laneM;
        const short8 a0 = *(const short8*)(gimg + srow * 64 + ch0);
        const short8 a1 = *(const short8*)(gimg + srow * 64 + ch1);

        float4v run = { -3.0e38f, -3.0e38f, -3.0e38f, -3.0e38f };
#pragma unroll
        for (int ct = 0; ct < 16; ++ct) {
            // compile-time conditions: only the 78 union tiles are emitted
            const bool c2 = (ct >= cLOW[rt]) && (ct <= cHIW[rt]);  // hc in win(hr)
            const bool c1 = (rt >= cLOW[ct]) && (rt <= cHIW[ct]);  // hr in win(hc)
            if (c1 || c2) {
                float4v acc = { 0.f, 0.f, 0.f, 0.f };
                acc = __builtin_amdgcn_mfma_f32_16x16x32_bf16(a0, B0[ct], acc, 0, 0, 0);
                acc = __builtin_amdgcn_mfma_f32_16x16x32_bf16(a1, B1[ct], acc, 0, 0, 0);
                if (c2) {   // s2: per-row running max
                    run.x = fmaxf(run.x, acc.x);
                    run.y = fmaxf(run.y, acc.y);
                    run.z = fmaxf(run.z, acc.z);
                    run.w = fmaxf(run.w, acc.w);
                }
                if (c1) {   // s1: quad-partial col-max (compile-time reg index)
                    const float t = fmaxf(fmaxf(acc.x, acc.y), fmaxf(acc.z, acc.w));
                    s1p[ct] = fmaxf(s1p[ct], t);
                }
            }
        }
        // s2 epilogue for this rt: DPP row-max + masked accumulate
        const float rx = rowmax16(run.x);
        const float ry = rowmax16(run.y);
        const float rz = rowmax16(run.z);
        const float rw = rowmax16(run.w);
        const float4v fw = *(const float4v*)(fcw + rt * 16 + q * 4);
        float t;
        t = msk * rx; dot += t * fw.x; sum += t; sq += t * rx;
        t = msk * ry; dot += t * fw.y; sum += t; sq += t * ry;
        t = msk * rz; dot += t * fw.z; sum += t; sq += t * rz;
        t = msk * rw; dot += t * fw.w; sum += t; sq += t * rw;
    }

    // ---- s1 epilogue: cross-quad max (shfl over 16/32), masked accumulate
#pragma unroll
    for (int ct = 0; ct < 16; ++ct) {
        float v = s1p[ct];
        v = fmaxf(v, __shfl_xor(v, 16, 64));
        v = fmaxf(v, __shfl_xor(v, 32, 64));   // col-max for s = ct*16 + laneM
        const float fv = fcw[ct * 16 + laneM];
        const float tt = msk1 * v;
        dot += tt * fv; sum += tt; sq += tt * v;
    }

    // ---- full-wave sum of the 3 scalars; lane 0 stores
    dot = wavesum64(dot);
    sum = wavesum64(sum);
    sq  = wavesum64(sq);
    if (lane == 0) {
        outDot[pair] = dot;
        outSum[pair] = sum;
        outSq[pair] = sq;
    }

    // ---- last-block fused finalize -------------------------------------
    __threadfence();                          // release our stores (cross-XCD)
    unsigned int t = 0u;
    if (lane == 0) t = atomicAdd(cnt, 1u);
    t = (unsigned int)__shfl((int)t, 0, 64);
    if (t != 2303u) return;
    __threadfence();                          // acquire all waves' stores

    // One wave handles all 2304 pairs: 36 pairs/lane, i = lane + 64*k.
    float S = 0.f, Q = 0.f;
    float dv[36];
#pragma unroll
    for (int k = 0; k < 36; ++k) {
        const int i = lane + 64 * k;
        dv[k] = outDot[i];
        S += outSum[i];
        Q += outSq[i];
    }
    float W = fcw[lane] + fcw[lane + 64] + fcw[lane + 128] + fcw[lane + 192];
    S = wavesum64(S);
    Q = wavesum64(Q);
    W = wavesum64(W);

    const float N1 = 1179648.0f;           // 4608 * 256 elements in BN1
    const float m1 = S / N1;
    const float v1 = Q / N1 - m1 * m1;     // biased var (torch training default)
    const float inv1 = rsqrtf(v1 + 1e-5f);
    const float g1 = bng[0], b1 = bnb[0], fb = fcb[0];
    const float g2 = lg[0], b2 = lb[0];
    const float cA = g1 * inv1;
    const float cB = 2.f * (b1 * W + fb) - cA * 2.f * m1 * W;

    float Sy = 0.f, Qy = 0.f;
    float yv[36];
#pragma unroll
    for (int k = 0; k < 36; ++k) {
        const float y = cA * dv[k] + cB;
        yv[k] = y;
        Sy += y;
        Qy += y * y;
    }
    Sy = wavesum64(Sy);
    Qy = wavesum64(Qy);

    const float m2 = Sy / 2304.0f;
    const float v2 = Qy / 2304.0f - m2 * m2;
    const float inv2 = rsqrtf(v2 + 1e-5f);
#pragma unroll
    for (int k = 0; k < 36; ++k) {
        const int i = lane + 64 * k;
        const float zz = g2 * (yv[k] - m2) * inv2 + b2;
        outp[i] = 1.0f / (1.0f + __expf(-zz));
    }
}

extern "C" void kernel_launch(void* const* d_in, const int* in_sizes, int n_in,
                              void* d_out, int out_size, void* d_ws, size_t ws_size,
                              hipStream_t stream) {
    const float* prob = (const float*)d_in[0];
    const float* gal  = (const float*)d_in[1];
    const float* bng  = (const float*)d_in[2];
    const float* bnb  = (const float*)d_in[3];
    const float* fcw  = (const float*)d_in[4];
    const float* fcb  = (const float*)d_in[5];
    const float* lg   = (const float*)d_in[6];
    const float* lb   = (const float*)d_in[7];

    unsigned short* preT = (unsigned short*)d_ws;        // 96*16384 bf16 = 3 MB
    float* ws = (float*)((char*)d_ws + 96 * 16384 * sizeof(unsigned short));
    float* dDot = ws;            // [2304]
    float* dSum = ws + 2304;     // [2304]
    float* dSq  = ws + 4608;     // [2304]
    unsigned int* cnt = (unsigned int*)(ws + 6912);      // ticket counter

    hipLaunchKernelGGL(pretranspose_kernel, dim3(384), dim3(64), 0, stream,
                       prob, gal, preT, cnt);
    hipLaunchKernelGGL(score_pam_kernel, dim3(2304), dim3(64), 0, stream,
                       preT, fcw, dDot, dSum, dSq, cnt,
                       bng, bnb, fcb, lg, lb, (float*)d_out);
}

// Round 2
// 92.815 us; speedup vs baseline: 1.7931x; 1.7931x over previous
//
#include <hip/hip_runtime.h>

typedef __attribute__((ext_vector_type(8))) short short8;
typedef __attribute__((ext_vector_type(4))) float float4v;

__device__ __forceinline__ unsigned short f2bf(float f) {
    unsigned int x = __builtin_bit_cast(unsigned int, f);
    x += 0x7FFF + ((x >> 16) & 1);   // round-to-nearest-even
    return (unsigned short)(x >> 16);
}

struct __align__(16) U16x8 { unsigned short u[8]; };

// DPP cross-lane ops within 16-lane rows — pure VALU.
template <int CTRL>
__device__ __forceinline__ float dppmaxf(float x) {
    int y = __builtin_amdgcn_update_dpp(0, __builtin_bit_cast(int, x),
                                        CTRL, 0xF, 0xF, true);
    return fmaxf(x, __builtin_bit_cast(float, y));
}
template <int CTRL>
__device__ __forceinline__ float dppaddf(float x) {
    int y = __builtin_amdgcn_update_dpp(0, __builtin_bit_cast(int, x),
                                        CTRL, 0xF, 0xF, true);
    return x + __builtin_bit_cast(float, y);
}
__device__ __forceinline__ float rowmax16(float x) {
    x = dppmaxf<0xB1>(x);    // quad_perm [1,0,3,2]
    x = dppmaxf<0x4E>(x);    // quad_perm [2,3,0,1]
    x = dppmaxf<0x141>(x);   // row_half_mirror
    x = dppmaxf<0x140>(x);   // row_mirror
    return x;
}
__device__ __forceinline__ float rowsum16(float x) {
    x = dppaddf<0xB1>(x);
    x = dppaddf<0x4E>(x);
    x = dppaddf<0x141>(x);
    x = dppaddf<0x140>(x);
    return x;
}

// Kernel 0: f32 [img][64c][256s] -> bf16 [img][s][c] with chunk XOR swizzle
// (chunk' = (c/8) ^ (s%8)). imgs 0..47 = probe, 48..95 = gallery.
// 384 single-wave blocks: img = bid>>2, s-quarter = bid&3.
__global__ __launch_bounds__(64) void pretranspose_kernel(
    const float* __restrict__ prob,
    const float* __restrict__ gal,
    unsigned short* __restrict__ outT)   // [96][16384] bf16
{
    const int img = blockIdx.x >> 2;
    const int quarter = blockIdx.x & 3;
    const float* src = (img < 48) ? (prob + img * 16384)
                                  : (gal + (img - 48) * 16384);
    unsigned short* dst = outT + img * 16384;
    const int tid = threadIdx.x;          // 0..63
    const int c0 = (tid & 7) * 8;
    const int s0 = quarter * 64 + (tid >> 3) * 8;
    unsigned short v[8][8];
#pragma unroll
    for (int i = 0; i < 8; ++i) {
        const float* p = src + (c0 + i) * 256 + s0;
        const float4v f0 = *(const float4v*)(p);
        const float4v f1 = *(const float4v*)(p + 4);
        v[i][0] = f2bf(f0.x); v[i][1] = f2bf(f0.y);
        v[i][2] = f2bf(f0.z); v[i][3] = f2bf(f0.w);
        v[i][4] = f2bf(f1.x); v[i][5] = f2bf(f1.y);
        v[i][6] = f2bf(f1.z); v[i][7] = f2bf(f1.w);
    }
#pragma unroll
    for (int j = 0; j < 8; ++j) {
        U16x8 o;
#pragma unroll
        for (int i = 0; i < 8; ++i) o.u[i] = v[i][j];
        const int srow = s0 + j;
        const int off = srow * 64 + (((c0 >> 3) ^ (srow & 7)) << 3);
        *(U16x8*)(dst + off) = o;
    }
}

// Kernel A: ONE WAVE = ONE PAIR, with the ENTIRE PROBE IMAGE held in
// registers: 32 KB = 512 B/lane = 128 VGPRs (B0[16]+B1[16] short8).
// 32 independent up-front loads (max MLP, no spill: ~180 live VGPRs under
// the 256 cap of __launch_bounds__(64,2)), then the 78-tile body is
// register-fed. Branch-free full unroll, zero LDS, zero barriers.
// acc.i = score(r = rt*16+q*4+i, s = ct*16+laneM).
//
// NOTE (R1 post-mortem): do NOT fuse the finalize here via a last-block
// ticket. Per-wave __threadfence() at device scope on gfx950 emits
// cache writeback/invalidate to bridge the non-coherent per-XCD L2s;
// 2304 of them destroyed L1/L2 locality and serialized on one atomic
// cacheline (+90 µs, MfmaUtil 2.2%). The kernel-boundary dependency is
// the cheap way to get cross-XCD visibility (one flush, not 2304).
__global__ __launch_bounds__(64, 2) void score_pam_kernel(
    const unsigned short* __restrict__ preT,  // [96][16384] bf16 pre-transposed
    const float* __restrict__ fcw,            // [256] f32
    float* __restrict__ outDot,               // [2304]
    float* __restrict__ outSum,               // [2304]
    float* __restrict__ outSq)                // [2304]
{
    constexpr int cLOW[16] = {0,0,0,1,2,3,4,5,6,7,8,9,10,11,12,12};
    constexpr int cHIW[16] = {3,3,3,4,5,6,7,8,9,10,11,12,13,14,15,15};

    const int lane = threadIdx.x;              // 0..63 (one wave)
    const int bid = blockIdx.x;                // 0..2303
    const int pair = (bid & 255) * 9 + (bid >> 8);   // CU-affine bijection
    const int ip = pair / 48;
    const int ig = pair % 48;
    const unsigned short* pimg = preT + ip * 16384;         // B: probe (cols)
    const unsigned short* gimg = preT + (48 + ig) * 16384;  // A: gallery (rows)

    const int laneM = lane & 15;
    const int q = lane >> 4;
    const int z = laneM & 7;
    const int ch0 = (q ^ z) << 3;
    const int ch1 = ((q + 4) ^ z) << 3;

    // ---- register-resident probe: 32 independent loads, 128 VGPRs
    short8 B0[16], B1[16];
#pragma unroll
    for (int ct = 0; ct < 16; ++ct) {
        const int sl = ct * 16 + laneM;
        B0[ct] = *(const short8*)(pimg + sl * 64 + ch0);
        B1[ct] = *(const short8*)(pimg + sl * 64 + ch1);
    }

    float dot = 0.f, sum = 0.f, sq = 0.f;
    const float msk = (laneM == 0) ? 1.0f : 0.0f;   // one lane per s2 row copy
    const float msk1 = (q == 0) ? 1.0f : 0.0f;      // one quad per s1 col copy

    float s1p[16];
#pragma unroll
    for (int i = 0; i < 16; ++i) s1p[i] = -3.0e38f;

#pragma unroll
    for (int rt = 0; rt < 16; ++rt) {
        const int srow = rt * 16 + laneM;
        const short8 a0 = *(const short8*)(gimg + srow * 64 + ch0);
        const short8 a1 = *(const short8*)(gimg + srow * 64 + ch1);

        float4v run = { -3.0e38f, -3.0e38f, -3.0e38f, -3.0e38f };
#pragma unroll
        for (int ct = 0; ct < 16; ++ct) {
            // compile-time conditions: only the 78 union tiles are emitted
            const bool c2 = (ct >= cLOW[rt]) && (ct <= cHIW[rt]);  // hc in win(hr)
            const bool c1 = (rt >= cLOW[ct]) && (rt <= cHIW[ct]);  // hr in win(hc)
            if (c1 || c2) {
                float4v acc = { 0.f, 0.f, 0.f, 0.f };
                acc = __builtin_amdgcn_mfma_f32_16x16x32_bf16(a0, B0[ct], acc, 0, 0, 0);
                acc = __builtin_amdgcn_mfma_f32_16x16x32_bf16(a1, B1[ct], acc, 0, 0, 0);
                if (c2) {   // s2: per-row running max
                    run.x = fmaxf(run.x, acc.x);
                    run.y = fmaxf(run.y, acc.y);
                    run.z = fmaxf(run.z, acc.z);
                    run.w = fmaxf(run.w, acc.w);
                }
                if (c1) {   // s1: quad-partial col-max (compile-time reg index)
                    const float t = fmaxf(fmaxf(acc.x, acc.y), fmaxf(acc.z, acc.w));
                    s1p[ct] = fmaxf(s1p[ct], t);
                }
            }
        }
        // s2 epilogue for this rt: DPP row-max + masked accumulate
        const float rx = rowmax16(run.x);
        const float ry = rowmax16(run.y);
        const float rz = rowmax16(run.z);
        const float rw = rowmax16(run.w);
        const float4v fw = *(const float4v*)(fcw + rt * 16 + q * 4);
        float t;
        t = msk * rx; dot += t * fw.x; sum += t; sq += t * rx;
        t = msk * ry; dot += t * fw.y; sum += t; sq += t * ry;
        t = msk * rz; dot += t * fw.z; sum += t; sq += t * rz;
        t = msk * rw; dot += t * fw.w; sum += t; sq += t * rw;
    }

    // ---- s1 epilogue: cross-quad max (shfl over 16/32), masked accumulate
#pragma unroll
    for (int ct = 0; ct < 16; ++ct) {
        float v = s1p[ct];
        v = fmaxf(v, __shfl_xor(v, 16, 64));
        v = fmaxf(v, __shfl_xor(v, 32, 64));   // col-max for s = ct*16 + laneM
        const float fv = fcw[ct * 16 + laneM];
        const float tt = msk1 * v;
        dot += tt * fv; sum += tt; sq += tt * v;
    }

    // ---- full-wave sum of the 3 scalars; lane 0 stores
    dot = rowsum16(dot); dot += __shfl_xor(dot, 16, 64); dot += __shfl_xor(dot, 32, 64);
    sum = rowsum16(sum); sum += __shfl_xor(sum, 16, 64); sum += __shfl_xor(sum, 32, 64);
    sq  = rowsum16(sq);  sq  += __shfl_xor(sq, 16, 64);  sq  += __shfl_xor(sq, 32, 64);
    if (lane == 0) {
        outDot[pair] = dot;
        outSum[pair] = sum;
        outSq[pair] = sq;
    }
}

// Kernel B: single block. Global BN1 stats from per-pair sums, fc (linear),
// pair-sum, BN2 over 2304, sigmoid, f32 store.
__global__ __launch_bounds__(256) void finalize_kernel(
    const float* __restrict__ dDot,
    const float* __restrict__ dSum,
    const float* __restrict__ dSq,
    const float* __restrict__ bng,
    const float* __restrict__ bnb,
    const float* __restrict__ fcw,
    const float* __restrict__ fcb,
    const float* __restrict__ lg,
    const float* __restrict__ lb,
    float* __restrict__ outp)   // [2304] f32
{
    __shared__ float red[12];
    const int tid = threadIdx.x;
    const int lane = tid & 63;
    const int w = tid >> 6;

    float S = 0.f, Q = 0.f;
    float dv[9];
#pragma unroll
    for (int k = 0; k < 9; ++k) {
        const int i = tid + 256 * k;
        dv[k] = dDot[i];
        S += dSum[i];
        Q += dSq[i];
    }
    float Wj = fcw[tid];
#pragma unroll
    for (int d = 32; d >= 1; d >>= 1) {
        S += __shfl_down(S, d, 64);
        Q += __shfl_down(Q, d, 64);
        Wj += __shfl_down(Wj, d, 64);
    }
    if (lane == 0) { red[w] = S; red[4 + w] = Q; red[8 + w] = Wj; }
    __syncthreads();
    S = red[0] + red[1] + red[2] + red[3];
    Q = red[4] + red[5] + red[6] + red[7];
    const float W = red[8] + red[9] + red[10] + red[11];
    __syncthreads();

    const float N1 = 1179648.0f;           // 4608 * 256 elements in BN1
    const float m1 = S / N1;
    const float v1 = Q / N1 - m1 * m1;     // biased var (torch training default)
    const float inv1 = rsqrtf(v1 + 1e-5f);
    const float g1 = bng[0], b1 = bnb[0], fb = fcb[0];
    const float g2 = lg[0], b2 = lb[0];
    const float cA = g1 * inv1;
    const float cB = 2.f * (b1 * W + fb) - cA * 2.f * m1 * W;

    float Sy = 0.f, Qy = 0.f;
    float yv[9];
#pragma unroll
    for (int k = 0; k < 9; ++k) {
        const float y = cA * dv[k] + cB;
        yv[k] = y;
        Sy += y;
        Qy += y * y;
    }
#pragma unroll
    for (int d = 32; d >= 1; d >>= 1) {
        Sy += __shfl_down(Sy, d, 64);
        Qy += __shfl_down(Qy, d, 64);
    }
    if (lane == 0) { red[w] = Sy; red[4 + w] = Qy; }
    __syncthreads();
    Sy = red[0] + red[1] + red[2] + red[3];
    Qy = red[4] + red[5] + red[6] + red[7];

    const float m2 = Sy / 2304.0f;
    const float v2 = Qy / 2304.0f - m2 * m2;
    const float inv2 = rsqrtf(v2 + 1e-5f);
#pragma unroll
    for (int k = 0; k < 9; ++k) {
        const int i = tid + 256 * k;
        const float z = g2 * (yv[k] - m2) * inv2 + b2;
        outp[i] = 1.0f / (1.0f + __expf(-z));
    }
}

extern "C" void kernel_launch(void* const* d_in, const int* in_sizes, int n_in,
                              void* d_out, int out_size, void* d_ws, size_t ws_size,
                              hipStream_t stream) {
    const float* prob = (const float*)d_in[0];
    const float* gal  = (const float*)d_in[1];
    const float* bng  = (const float*)d_in[2];
    const float* bnb  = (const float*)d_in[3];
    const float* fcw  = (const float*)d_in[4];
    const float* fcb  = (const float*)d_in[5];
    const float* lg   = (const float*)d_in[6];
    const float* lb   = (const float*)d_in[7];

    unsigned short* preT = (unsigned short*)d_ws;        // 96*16384 bf16 = 3 MB
    float* ws = (float*)((char*)d_ws + 96 * 16384 * sizeof(unsigned short));
    float* dDot = ws;            // [2304]
    float* dSum = ws + 2304;     // [2304]
    float* dSq  = ws + 4608;     // [2304]

    hipLaunchKernelGGL(pretranspose_kernel, dim3(384), dim3(64), 0, stream,
                       prob, gal, preT);
    hipLaunchKernelGGL(score_pam_kernel, dim3(2304), dim3(64), 0, stream,
                       preT, fcw, dDot, dSum, dSq);
    hipLaunchKernelGGL(finalize_kernel, dim3(1), dim3(256), 0, stream,
                       dDot, dSum, dSq, bng, bnb, fcw, fcb, lg, lb,
                       (float*)d_out);
}